// Round 5
// baseline (234.793 us; speedup 1.0000x reference)
//
#include <hip/hip_runtime.h>
#include <math.h>

#define BDIM 8
#define IMG 224
#define PP 16
#define GG 14
#define NN 196
#define PD 256
#define DD 128
#define DFFV 256
#define CC 1000
#define NTILE 49

#define NEGINF (-INFINITY)

// ============ K1: embed + qkv(layer0). grid (14, B), 256 threads ============
__global__ void embed_qkv_kernel(const float* __restrict__ x, const float* __restrict__ eW,
                                 const float* __restrict__ pos,
                                 const float* __restrict__ qW, const float* __restrict__ kW,
                                 const float* __restrict__ vW,
                                 float* __restrict__ h, float* __restrict__ q,
                                 float* __restrict__ k, float* __restrict__ v) {
  int b = blockIdx.y, gi = blockIdx.x;
  __shared__ float patch[GG][PD];   // 14 KB
  __shared__ float hrow[GG][DD];    // 7 KB
  __shared__ float mxs[GG];
  int t = threadIdx.x;
  for (int e = t; e < GG * 64; e += 256) {
    int gj = e >> 6, r = e & 63, pi = r >> 2, pj4 = r & 3;
    float4 val = *reinterpret_cast<const float4*>(
        x + (size_t)(b * IMG + gi * PP + pi) * IMG + gj * PP + pj4 * 4);
    *reinterpret_cast<float4*>(&patch[gj][pi * PP + pj4 * 4]) = val;
  }
  __syncthreads();
  int d = t & 127, half = t >> 7;
  {
    float acc[7];
#pragma unroll
    for (int kk = 0; kk < 7; kk++) acc[kk] = NEGINF;
    const float4* W4 = reinterpret_cast<const float4*>(eW + (size_t)d * PD);
#pragma unroll 4
    for (int j4 = 0; j4 < PD / 4; j4++) {
      float4 w = W4[j4];
#pragma unroll
      for (int kk = 0; kk < 7; kk++) {
        int gj = half * 7 + kk;
        acc[kk] = fmaxf(acc[kk], patch[gj][j4 * 4 + 0] + w.x);
        acc[kk] = fmaxf(acc[kk], patch[gj][j4 * 4 + 1] + w.y);
        acc[kk] = fmaxf(acc[kk], patch[gj][j4 * 4 + 2] + w.z);
        acc[kk] = fmaxf(acc[kk], patch[gj][j4 * 4 + 3] + w.w);
      }
    }
#pragma unroll
    for (int kk = 0; kk < 7; kk++) {
      int gj = half * 7 + kk, n = gi * GG + gj;
      float hv = acc[kk] + pos[(size_t)n * DD + d];
      hrow[gj][d] = hv;
      h[(size_t)(b * NN + n) * DD + d] = hv;
    }
  }
  __syncthreads();
  // row maxes: 224 threads = 14 rows x 16 lanes, 8 elems each
  if (t < GG * 16) {
    int r = t >> 4, sub = t & 15;
    float m = NEGINF;
#pragma unroll
    for (int e = 0; e < 8; e++) m = fmaxf(m, hrow[r][sub * 8 + e]);
#pragma unroll
    for (int mask = 8; mask >= 1; mask >>= 1) m = fmaxf(m, __shfl_xor(m, mask, 16));
    if (sub == 0) mxs[r] = m;
  }
  __syncthreads();
  // q (threads 0-127) and k (threads 128-255), pnorm folded to output
  {
    int m = t >> 7, i = t & 127;
    const float* W = (m == 0) ? qW : kW;
    float* dst = (m == 0) ? q : k;
    const float4* W4 = reinterpret_cast<const float4*>(W + (size_t)i * DD);
    float acc[GG];
#pragma unroll
    for (int r = 0; r < GG; r++) acc[r] = NEGINF;
#pragma unroll 2
    for (int j4 = 0; j4 < DD / 4; j4++) {
      float4 w = W4[j4];
#pragma unroll
      for (int r = 0; r < GG; r++) {
        acc[r] = fmaxf(acc[r], hrow[r][j4 * 4 + 0] + w.x);
        acc[r] = fmaxf(acc[r], hrow[r][j4 * 4 + 1] + w.y);
        acc[r] = fmaxf(acc[r], hrow[r][j4 * 4 + 2] + w.z);
        acc[r] = fmaxf(acc[r], hrow[r][j4 * 4 + 3] + w.w);
      }
    }
#pragma unroll
    for (int r = 0; r < GG; r++)
      dst[(size_t)(b * NN + gi * GG + r) * DD + i] = acc[r] - mxs[r];
  }
  // v (threads 0-127)
  if (t < 128) {
    const float4* W4 = reinterpret_cast<const float4*>(vW + (size_t)t * DD);
    float acc[GG];
#pragma unroll
    for (int r = 0; r < GG; r++) acc[r] = NEGINF;
#pragma unroll 2
    for (int j4 = 0; j4 < DD / 4; j4++) {
      float4 w = W4[j4];
#pragma unroll
      for (int r = 0; r < GG; r++) {
        acc[r] = fmaxf(acc[r], hrow[r][j4 * 4 + 0] + w.x);
        acc[r] = fmaxf(acc[r], hrow[r][j4 * 4 + 1] + w.y);
        acc[r] = fmaxf(acc[r], hrow[r][j4 * 4 + 2] + w.z);
        acc[r] = fmaxf(acc[r], hrow[r][j4 * 4 + 3] + w.w);
      }
    }
#pragma unroll
    for (int r = 0; r < GG; r++)
      v[(size_t)(b * NN + gi * GG + r) * DD + t] = acc[r] - mxs[r];
  }
}

// ======= K2/K3: attn + ffn1 + ffn2 (+ qkv_next | partial pool) =======
// grid (49, B), 256 threads, 4 rows per block.
template <int LAST>
__global__ void layer_kernel(const float* __restrict__ q, const float* __restrict__ k,
                             const float* __restrict__ v, float* __restrict__ h,
                             const float* __restrict__ f1W, const float* __restrict__ f2W,
                             const float* __restrict__ tau,
                             const float* __restrict__ qWn, const float* __restrict__ kWn,
                             const float* __restrict__ vWn,
                             float* __restrict__ qn, float* __restrict__ kn,
                             float* __restrict__ vn, float* __restrict__ pp) {
  int it = blockIdx.x, b = blockIdx.y, i0 = it * 4;
  __shared__ float qs[4][DD];       // 2 KB
  __shared__ float sc[4][NN];       // 3.1 KB
  __shared__ float ored[8][4][DD];  // 16 KB
  __shared__ float hcur[4][DD];     // 2 KB
  __shared__ float h1s[4][DFFV];    // 4 KB
  __shared__ float part[2][4][DD];  // 4 KB
  __shared__ float red[2][4];
  __shared__ float m2[4];
  int t = threadIdx.x;
  if (t < 128) {
    float4 val = reinterpret_cast<const float4*>(q + (size_t)(b * NN + i0) * DD)[t];
    *reinterpret_cast<float4*>(&qs[0][0] + t * 4) = val;
  } else {
    int tt = t - 128;
    float4 val = reinterpret_cast<const float4*>(h + (size_t)(b * NN + i0) * DD)[tt];
    *reinterpret_cast<float4*>(&hcur[0][0] + tt * 4) = val;
  }
  __syncthreads();
  // --- scores: thread t = key index ---
  if (t < NN) {
    const float4* k4 = reinterpret_cast<const float4*>(k + (size_t)(b * NN + t) * DD);
    float s0 = NEGINF, s1 = NEGINF, s2 = NEGINF, s3 = NEGINF;
#pragma unroll 4
    for (int d4 = 0; d4 < DD / 4; d4++) {
      float4 kv = k4[d4];
      s0 = fmaxf(s0, qs[0][d4 * 4 + 0] + kv.x); s0 = fmaxf(s0, qs[0][d4 * 4 + 1] + kv.y);
      s0 = fmaxf(s0, qs[0][d4 * 4 + 2] + kv.z); s0 = fmaxf(s0, qs[0][d4 * 4 + 3] + kv.w);
      s1 = fmaxf(s1, qs[1][d4 * 4 + 0] + kv.x); s1 = fmaxf(s1, qs[1][d4 * 4 + 1] + kv.y);
      s1 = fmaxf(s1, qs[1][d4 * 4 + 2] + kv.z); s1 = fmaxf(s1, qs[1][d4 * 4 + 3] + kv.w);
      s2 = fmaxf(s2, qs[2][d4 * 4 + 0] + kv.x); s2 = fmaxf(s2, qs[2][d4 * 4 + 1] + kv.y);
      s2 = fmaxf(s2, qs[2][d4 * 4 + 2] + kv.z); s2 = fmaxf(s2, qs[2][d4 * 4 + 3] + kv.w);
      s3 = fmaxf(s3, qs[3][d4 * 4 + 0] + kv.x); s3 = fmaxf(s3, qs[3][d4 * 4 + 1] + kv.y);
      s3 = fmaxf(s3, qs[3][d4 * 4 + 2] + kv.z); s3 = fmaxf(s3, qs[3][d4 * 4 + 3] + kv.w);
    }
    sc[0][t] = s0; sc[1][t] = s1; sc[2][t] = s2; sc[3][t] = s3;
  }
  __syncthreads();
  // --- PV ---
  {
    int d4 = t & 31, jg = t >> 5;
    float4 o0 = {NEGINF, NEGINF, NEGINF, NEGINF};
    float4 o1 = o0, o2 = o0, o3 = o0;
#pragma unroll 5
    for (int j = jg; j < NN; j += 8) {
      float4 vv = *reinterpret_cast<const float4*>(v + (size_t)(b * NN + j) * DD + d4 * 4);
      float c0 = sc[0][j], c1 = sc[1][j], c2 = sc[2][j], c3 = sc[3][j];
      o0.x = fmaxf(o0.x, c0 + vv.x); o0.y = fmaxf(o0.y, c0 + vv.y);
      o0.z = fmaxf(o0.z, c0 + vv.z); o0.w = fmaxf(o0.w, c0 + vv.w);
      o1.x = fmaxf(o1.x, c1 + vv.x); o1.y = fmaxf(o1.y, c1 + vv.y);
      o1.z = fmaxf(o1.z, c1 + vv.z); o1.w = fmaxf(o1.w, c1 + vv.w);
      o2.x = fmaxf(o2.x, c2 + vv.x); o2.y = fmaxf(o2.y, c2 + vv.y);
      o2.z = fmaxf(o2.z, c2 + vv.z); o2.w = fmaxf(o2.w, c2 + vv.w);
      o3.x = fmaxf(o3.x, c3 + vv.x); o3.y = fmaxf(o3.y, c3 + vv.y);
      o3.z = fmaxf(o3.z, c3 + vv.z); o3.w = fmaxf(o3.w, c3 + vv.w);
    }
    *reinterpret_cast<float4*>(&ored[jg][0][d4 * 4]) = o0;
    *reinterpret_cast<float4*>(&ored[jg][1][d4 * 4]) = o1;
    *reinterpret_cast<float4*>(&ored[jg][2][d4 * 4]) = o2;
    *reinterpret_cast<float4*>(&ored[jg][3][d4 * 4]) = o3;
  }
  __syncthreads();
  // reduce across 8 j-groups + row-max of attn out
  if (t < DD) {
    int lane = t & 63, wv = t >> 6;
#pragma unroll
    for (int r = 0; r < 4; r++) {
      float m = ored[0][r][t];
#pragma unroll
      for (int g = 1; g < 8; g++) m = fmaxf(m, ored[g][r][t]);
      ored[0][r][t] = m;
      float mv = m;
#pragma unroll
      for (int mask = 32; mask >= 1; mask >>= 1) mv = fmaxf(mv, __shfl_xor(mv, mask));
      if (lane == 0) red[wv][r] = mv;
    }
  }
  __syncthreads();
  // residual: hcur = max(hcur, a - amax)
  if (t < DD) {
#pragma unroll
    for (int r = 0; r < 4; r++) {
      float amax = fmaxf(red[0][r], red[1][r]);
      hcur[r][t] = fmaxf(hcur[r][t], ored[0][r][t] - amax);
    }
  }
  __syncthreads();
  // row-max of new h (for ffn1's folded pnorm)
  if (t < 128) {
    int r = t >> 5, l = t & 31;
    float m = fmaxf(fmaxf(hcur[r][l], hcur[r][l + 32]), fmaxf(hcur[r][l + 64], hcur[r][l + 96]));
#pragma unroll
    for (int mask = 16; mask >= 1; mask >>= 1) m = fmaxf(m, __shfl_xor(m, mask));
    if (l == 0) m2[r] = m;
  }
  __syncthreads();
  // --- ffn1: thread t owns DFF dim t ---
  {
    float tv = tau[0];
    const float4* W4 = reinterpret_cast<const float4*>(f1W + (size_t)t * DD);
    float acc[4];
#pragma unroll
    for (int r = 0; r < 4; r++) acc[r] = NEGINF;
#pragma unroll 4
    for (int j4 = 0; j4 < DD / 4; j4++) {
      float4 w = W4[j4];
#pragma unroll
      for (int r = 0; r < 4; r++) {
        acc[r] = fmaxf(acc[r], hcur[r][j4 * 4 + 0] + w.x);
        acc[r] = fmaxf(acc[r], hcur[r][j4 * 4 + 1] + w.y);
        acc[r] = fmaxf(acc[r], hcur[r][j4 * 4 + 2] + w.z);
        acc[r] = fmaxf(acc[r], hcur[r][j4 * 4 + 3] + w.w);
      }
    }
#pragma unroll
    for (int r = 0; r < 4; r++) h1s[r][t] = fmaxf(acc[r] - m2[r], tv);
  }
  __syncthreads();
  // --- ffn2: split DFF over 2 halves ---
  {
    int i = t & 127, jh = t >> 7;
    const float4* W4 = reinterpret_cast<const float4*>(f2W + (size_t)i * DFFV) + jh * 32;
    float acc[4];
#pragma unroll
    for (int r = 0; r < 4; r++) acc[r] = NEGINF;
#pragma unroll 4
    for (int j4 = 0; j4 < 32; j4++) {
      float4 w = W4[j4];
      int jb = jh * 128 + j4 * 4;
#pragma unroll
      for (int r = 0; r < 4; r++) {
        acc[r] = fmaxf(acc[r], h1s[r][jb + 0] + w.x);
        acc[r] = fmaxf(acc[r], h1s[r][jb + 1] + w.y);
        acc[r] = fmaxf(acc[r], h1s[r][jb + 2] + w.z);
        acc[r] = fmaxf(acc[r], h1s[r][jb + 3] + w.w);
      }
    }
#pragma unroll
    for (int r = 0; r < 4; r++) part[jh][r][i] = acc[r];
  }
  __syncthreads();
  if (t < DD) {
    int lane = t & 63, wv = t >> 6;
#pragma unroll
    for (int r = 0; r < 4; r++) {
      float m = fmaxf(part[0][r][t], part[1][r][t]);
      float mv = m;
#pragma unroll
      for (int mask = 32; mask >= 1; mask >>= 1) mv = fmaxf(mv, __shfl_xor(mv, mask));
      if (lane == 0) red[wv][r] = mv;
    }
  }
  __syncthreads();
  // ff residual: h_final = max(hcur, ff - ffmax); write global, keep in LDS
  if (t < DD) {
#pragma unroll
    for (int r = 0; r < 4; r++) {
      float ffmax = fmaxf(red[0][r], red[1][r]);
      float hv = fmaxf(hcur[r][t], fmaxf(part[0][r][t], part[1][r][t]) - ffmax);
      hcur[r][t] = hv;
      h[(size_t)(b * NN + i0 + r) * DD + t] = hv;
    }
  }
  __syncthreads();
  if (LAST == 0) {
    // row-max of final h for next layer's folded pnorm
    if (t < 128) {
      int r = t >> 5, l = t & 31;
      float m = fmaxf(fmaxf(hcur[r][l], hcur[r][l + 32]), fmaxf(hcur[r][l + 64], hcur[r][l + 96]));
#pragma unroll
      for (int mask = 16; mask >= 1; mask >>= 1) m = fmaxf(m, __shfl_xor(m, mask));
      if (l == 0) m2[r] = m;
    }
    __syncthreads();
    // qkv for next layer: q (0-127), k (128-255), then v (0-127)
    {
      int m = t >> 7, i = t & 127;
      const float* W = (m == 0) ? qWn : kWn;
      float* dst = (m == 0) ? qn : kn;
      const float4* W4 = reinterpret_cast<const float4*>(W + (size_t)i * DD);
      float acc[4];
#pragma unroll
      for (int r = 0; r < 4; r++) acc[r] = NEGINF;
#pragma unroll 4
      for (int j4 = 0; j4 < DD / 4; j4++) {
        float4 w = W4[j4];
#pragma unroll
        for (int r = 0; r < 4; r++) {
          acc[r] = fmaxf(acc[r], hcur[r][j4 * 4 + 0] + w.x);
          acc[r] = fmaxf(acc[r], hcur[r][j4 * 4 + 1] + w.y);
          acc[r] = fmaxf(acc[r], hcur[r][j4 * 4 + 2] + w.z);
          acc[r] = fmaxf(acc[r], hcur[r][j4 * 4 + 3] + w.w);
        }
      }
#pragma unroll
      for (int r = 0; r < 4; r++)
        dst[(size_t)(b * NN + i0 + r) * DD + i] = acc[r] - m2[r];
    }
    if (t < 128) {
      const float4* W4 = reinterpret_cast<const float4*>(vWn + (size_t)t * DD);
      float acc[4];
#pragma unroll
      for (int r = 0; r < 4; r++) acc[r] = NEGINF;
#pragma unroll 4
      for (int j4 = 0; j4 < DD / 4; j4++) {
        float4 w = W4[j4];
#pragma unroll
        for (int r = 0; r < 4; r++) {
          acc[r] = fmaxf(acc[r], hcur[r][j4 * 4 + 0] + w.x);
          acc[r] = fmaxf(acc[r], hcur[r][j4 * 4 + 1] + w.y);
          acc[r] = fmaxf(acc[r], hcur[r][j4 * 4 + 2] + w.z);
          acc[r] = fmaxf(acc[r], hcur[r][j4 * 4 + 3] + w.w);
        }
      }
#pragma unroll
      for (int r = 0; r < 4; r++)
        vn[(size_t)(b * NN + i0 + r) * DD + t] = acc[r] - m2[r];
    }
  } else {
    // partial pool over this block's 4 rows
    if (t < 128) {
      float pm = fmaxf(fmaxf(hcur[0][t], hcur[1][t]), fmaxf(hcur[2][t], hcur[3][t]));
      pp[((size_t)b * NTILE + it) * DD + t] = pm;
    }
  }
}

// ============ K4: head. grid (32, B), 256 threads ============
__global__ void head_kernel(const float* __restrict__ pp, const float* __restrict__ hW,
                            const float* __restrict__ lscale, float* __restrict__ out) {
  int cc = blockIdx.x, b = blockIdx.y;
  __shared__ float plds[8][DD];
  __shared__ float pooled[DD];
  __shared__ float gred[8][32];
  int t = threadIdx.x;
  {
    int d4 = t & 31, ng = t >> 5;
    float4 pm = {NEGINF, NEGINF, NEGINF, NEGINF};
#pragma unroll 4
    for (int n = ng; n < NTILE; n += 8) {
      float4 hv = *reinterpret_cast<const float4*>(pp + ((size_t)b * NTILE + n) * DD + d4 * 4);
      pm.x = fmaxf(pm.x, hv.x); pm.y = fmaxf(pm.y, hv.y);
      pm.z = fmaxf(pm.z, hv.z); pm.w = fmaxf(pm.w, hv.w);
    }
    *reinterpret_cast<float4*>(&plds[ng][d4 * 4]) = pm;
  }
  __syncthreads();
  if (t < DD) {
    float m = plds[0][t];
#pragma unroll
    for (int g = 1; g < 8; g++) m = fmaxf(m, plds[g][t]);
    pooled[t] = m;
  }
  __syncthreads();
  int cl = t & 31, ds = t >> 5;
  int c = cc * 32 + cl;
  float acc = NEGINF;
  if (c < CC) {
    const float4* W4 = reinterpret_cast<const float4*>(hW + (size_t)c * DD) + ds * 4;
#pragma unroll
    for (int kk = 0; kk < 4; kk++) {
      float4 w = W4[kk];
      int db = ds * 16 + kk * 4;
      acc = fmaxf(acc, pooled[db + 0] + w.x);
      acc = fmaxf(acc, pooled[db + 1] + w.y);
      acc = fmaxf(acc, pooled[db + 2] + w.z);
      acc = fmaxf(acc, pooled[db + 3] + w.w);
    }
  }
  gred[ds][cl] = acc;
  __syncthreads();
  if (t < 32) {
    int c2 = cc * 32 + t;
    if (c2 < CC) {
      float m = gred[0][t];
#pragma unroll
      for (int g = 1; g < 8; g++) m = fmaxf(m, gred[g][t]);
      out[(size_t)b * CC + c2] = m * lscale[0];
    }
  }
}

extern "C" void kernel_launch(void* const* d_in, const int* in_sizes, int n_in,
                              void* d_out, int out_size, void* d_ws, size_t ws_size,
                              hipStream_t stream) {
  const float* x = (const float*)d_in[0];
  const float* embed_W = (const float*)d_in[1];
  const float* pos = (const float*)d_in[2];
  const float* qW[2] = {(const float*)d_in[3], (const float*)d_in[9]};
  const float* kW[2] = {(const float*)d_in[4], (const float*)d_in[10]};
  const float* vW[2] = {(const float*)d_in[5], (const float*)d_in[11]};
  const float* f1W[2] = {(const float*)d_in[6], (const float*)d_in[12]};
  const float* f2W[2] = {(const float*)d_in[7], (const float*)d_in[13]};
  const float* tau[2] = {(const float*)d_in[8], (const float*)d_in[14]};
  const float* headW = (const float*)d_in[15];
  const float* lscale = (const float*)d_in[16];
  float* out = (float*)d_out;

  float* ws = (float*)d_ws;
  size_t o = 0;
  float* h = ws + o; o += (size_t)BDIM * NN * DD;
  float* q0 = ws + o; o += (size_t)BDIM * NN * DD;
  float* k0 = ws + o; o += (size_t)BDIM * NN * DD;
  float* v0 = ws + o; o += (size_t)BDIM * NN * DD;
  float* q1 = ws + o; o += (size_t)BDIM * NN * DD;
  float* k1 = ws + o; o += (size_t)BDIM * NN * DD;
  float* v1 = ws + o; o += (size_t)BDIM * NN * DD;
  float* pp = ws + o; o += (size_t)BDIM * NTILE * DD;

  embed_qkv_kernel<<<dim3(GG, BDIM), 256, 0, stream>>>(
      x, embed_W, pos, qW[0], kW[0], vW[0], h, q0, k0, v0);
  layer_kernel<0><<<dim3(NTILE, BDIM), 256, 0, stream>>>(
      q0, k0, v0, h, f1W[0], f2W[0], tau[0],
      qW[1], kW[1], vW[1], q1, k1, v1, nullptr);
  layer_kernel<1><<<dim3(NTILE, BDIM), 256, 0, stream>>>(
      q1, k1, v1, h, f1W[1], f2W[1], tau[1],
      nullptr, nullptr, nullptr, nullptr, nullptr, nullptr, pp);
  head_kernel<<<dim3(32, BDIM), 256, 0, stream>>>(pp, headW, lscale, out);
}